// Round 19
// baseline (92.395 us; speedup 1.0000x reference)
//
#include <hip/hip_runtime.h>

#define NFEAT 5
#define KDIM  80
#define VCNT  200
#define EPSF  1e-5f

#define DTH     0.39269908169872414f   /* 2*pi/16 */
#define INV_DTH 2.5464790894703254f    /* 16/(2*pi) */
#define LOG2E   1.4426950408889634f

/* LDS float offsets (27136 B, __launch_bounds__(256,5) -> 5 blocks/CU):
   phase A: [0..81)     wcnt[4][16] + basep[17] (ints)
            [256..2656)  pv[200][12] : f0..4, gr0..4, fv, pad
            [2656..6752) P[4][32][32] (8-chunk add-swizzle cc=(ch+(m>>1)+(m>>3))&7)
            row: [0..15)=group0 (r,{f0,f1,f2}), [16..31)=group1 (r,{f3,f4,S})
   phase B (P dead): ushort Ahi[5][16][104] = float[0..4160)
            [4160..4560) retf[400]
            [4560..4800) ret1p[3][80]
            ret1[80] reuses smem[0..80) after conv */
#define PV_OFF    256
#define P_OFF     2656
#define RETF_OFF  4160
#define RET1P_OFF 4560
#define LDS_F     6752

#define WT_ELEMS  (5*80*96)            /* 38400 per hi/lo plane */

typedef __attribute__((ext_vector_type(8))) short short8;
typedef __attribute__((ext_vector_type(4))) float f32x4;
typedef __attribute__((ext_vector_type(2))) float f32x2;

__device__ __forceinline__ unsigned bf16_rn_bits(float x) {
  const unsigned u = __float_as_uint(x);
  return (u + 0x7FFFu + ((u >> 16) & 1u)) >> 16;
}

/* ---- prep: W_conv -> transposed bf16 hi/lo [5][80 k'][96 k] in d_ws ---- */
__global__ void prep_w(const float* __restrict__ Wc,
                       unsigned short* __restrict__ whi,
                       unsigned short* __restrict__ wlo) {
  const int idx = blockIdx.x * 256 + threadIdx.x;
  if (idx >= WT_ELEMS) return;
  const int k  = idx % 96;
  const int kp = (idx / 96) % 80;
  const int ic = idx / (96 * 80);
  const float w = (k < 80) ? Wc[ic*6400 + k*80 + kp] : 0.0f;
  const unsigned hb = bf16_rn_bits(w);
  const float    hf = __uint_as_float(hb << 16);
  const unsigned lb = bf16_rn_bits(w - hf);
  whi[idx] = (unsigned short)hb;
  wlo[idx] = (unsigned short)lb;
}

__global__ __launch_bounds__(256, 5)
void masif_fused(const float* __restrict__ feat, const float* __restrict__ rho,
                 const float* __restrict__ theta, const float* __restrict__ mask,
                 const float* __restrict__ mu_rho_p,
                 const float* __restrict__ sigma_rho_p,
                 const float* __restrict__ sigma_theta_p,
                 const unsigned short* __restrict__ whi,
                 const unsigned short* __restrict__ wlo,
                 const float* __restrict__ bc,
                 const float* __restrict__ W1, const float* __restrict__ b1,
                 const float* __restrict__ W2, const float* __restrict__ b2,
                 float* __restrict__ out, int nB)
{
  __shared__ __align__(16) float smem[LDS_F];
  int*   wcnt  = (int*)smem;          /* [4][16] per-wave bin counts */
  int*   basep = (int*)smem + 64;     /* [17] */
  float* pv    = smem + PV_OFF;
  float* P     = smem + P_OFF;

  const int b    = blockIdx.x;
  if (b >= nB) return;
  const int tid  = threadIdx.x;
  const int lane = tid & 63;
  const int wv   = tid >> 6;

  const float stg = sigma_theta_p[0];
  const float nist2 = -(1.0f / (stg*stg + EPSF)) * DTH * DTH * LOG2E;

  /* ---------- prologue: per-vertex quantities in registers ---------- */
  int   my_iv = 999;
  float my_fv = 0.f;
  float myf[5], mygr[5];
  if (tid < VCNT) {
    const size_t gbase = (size_t)b * VCNT + tid;
    const float rh = rho[gbase];
    const float mk = mask[gbase];
    const float th = theta[gbase];
    const float sr = sigma_rho_p[0];
    const float nisr = -(1.0f / (sr*sr + EPSF)) * LOG2E;
    const float u = th * INV_DTH;
    int iv = (int)u; if (iv > 15) iv = 15;
    my_iv = iv;
    my_fv = u - (float)iv;
    #pragma unroll
    for (int j = 0; j < NFEAT; ++j) myf[j] = feat[gbase*NFEAT + j];
    #pragma unroll
    for (int r = 0; r < NFEAT; ++r) {
      const float d = rh - mu_rho_p[r*16];
      mygr[r] = exp2f(d*d*nisr) * mk;   /* rho-gauss * mask */
    }
  }

  /* ---------- ballot-based deterministic binning ---------- */
  unsigned long long mybal = 0ull;
  int mycnt = 0;
  #pragma unroll
  for (int bb = 0; bb < 16; ++bb) {
    const unsigned long long bal = __ballot(my_iv == bb);
    if (my_iv == bb) mybal = bal;
    if (lane == bb)  mycnt = (int)__popcll(bal);
  }
  if (lane < 16) wcnt[wv*16 + lane] = mycnt;
  __syncthreads();
  if (tid == 0) {
    int s0 = 0;
    #pragma unroll
    for (int bb = 0; bb < 16; ++bb) {
      basep[bb] = s0;
      s0 += wcnt[bb] + wcnt[16+bb] + wcnt[32+bb] + wcnt[48+bb];
    }
    basep[16] = s0;
  }
  __syncthreads();
  if (tid < VCNT) {
    int rk = (int)__popcll(mybal & ((1ull << lane) - 1ull));
    if (wv > 0) rk += wcnt[my_iv];
    if (wv > 1) rk += wcnt[16 + my_iv];
    if (wv > 2) rk += wcnt[32 + my_iv];
    const int p = basep[my_iv] + rk;
    float* pvr = pv + p*12;
    pvr[0]=myf[0];  pvr[1]=myf[1];  pvr[2]=myf[2];  pvr[3]=myf[3];  pvr[4]=myf[4];
    pvr[5]=mygr[0]; pvr[6]=mygr[1]; pvr[7]=mygr[2]; pvr[8]=mygr[3]; pvr[9]=mygr[4];
    pvr[10]=my_fv;  pvr[11]=0.f;
  }
  __syncthreads();

  /* ---------- single sweep x 4 passes: accumulate 30 ch -> dump P -> gather */
  const int kf  = tid >> 4;            /* gather role: rotation   */
  const int tt  = tid & 15;            /*              theta bin  */
  const int m   = (tid >> 1) & 31;     /* accum role: m-slice     */
  const int s   = tid & 1;             /*             vertex half */
  const int swz = (m >> 1) + (m >> 3); /* add-swizzle base        */
  const float fm = (float)(m - 15);

  f32x2 s2[16];
  #pragma unroll
  for (int q = 0; q < 16; ++q) s2[q] = f32x2{0.f, 0.f};

  #pragma unroll 1
  for (int p4 = 0; p4 < 4; ++p4) {
    const int bin = p4*4 + wv;         /* wave owns one bin per pass */
    const int p0 = basep[bin], p1 = basep[bin+1];
    f32x2 acc[5][3];
    #pragma unroll
    for (int r = 0; r < 5; ++r)
      #pragma unroll
      for (int q = 0; q < 3; ++q) acc[r][q] = f32x2{0.f, 0.f};

    for (int p = p0 + s; p < p1; p += 2) {
      const float4 x0 = *(const float4*)(pv + p*12);
      const float4 x1 = *(const float4*)(pv + p*12 + 4);
      const float4 x2 = *(const float4*)(pv + p*12 + 8);
      const float d = fm + x2.z;
      const float G = exp2f(d*d*nist2);
      const f32x2 v01 = {x0.x, x0.y};     /* f0, f1 */
      const f32x2 v23 = {x0.z, x0.w};     /* f2, f3 */
      const f32x2 v45 = {x1.x, 1.0f};     /* f4, S  */
      const float pa0 = x1.y*G, pa1 = x1.z*G, pa2 = x1.w*G,
                  pa3 = x2.x*G, pa4 = x2.y*G;
      acc[0][0] += v01*pa0; acc[0][1] += v23*pa0; acc[0][2] += v45*pa0;
      acc[1][0] += v01*pa1; acc[1][1] += v23*pa1; acc[1][2] += v45*pa1;
      acc[2][0] += v01*pa2; acc[2][1] += v23*pa2; acc[2][2] += v45*pa2;
      acc[3][0] += v01*pa3; acc[3][1] += v23*pa3; acc[3][2] += v45*pa3;
      acc[4][0] += v01*pa4; acc[4][1] += v23*pa4; acc[4][2] += v45*pa4;
    }

    /* combine the two vertex-halves (lane xor 1) */
    #pragma unroll
    for (int r = 0; r < 5; ++r)
      #pragma unroll
      for (int q = 0; q < 3; ++q) {
        acc[r][q].x += __shfl_xor(acc[r][q].x, 1);
        acc[r][q].y += __shfl_xor(acc[r][q].y, 1);
      }

    /* dump: logical row of 32 floats
         [r*3+0]=f0, [r*3+1]=f1, [r*3+2]=f2, [15]=0
         [16+r*3+0]=f3, [16+r*3+1]=f4, [16+r*3+2]=S, [31]=0
       lane s=0 writes chunks 0-3, s=1 writes chunks 4-7; contents are
       compile-time register refs (no runtime-indexed local array). */
    {
      float* Pb = P + (wv*32 + m)*32;
#define WRCH(CH, A, B, C, D) \
      *(float4*)(Pb + (((CH) + swz) & 7)*4) = make_float4(A, B, C, D)
      if (s == 0) {
        WRCH(0, acc[0][0].x, acc[0][0].y, acc[0][1].x, acc[1][0].x);
        WRCH(1, acc[1][0].y, acc[1][1].x, acc[2][0].x, acc[2][0].y);
        WRCH(2, acc[2][1].x, acc[3][0].x, acc[3][0].y, acc[3][1].x);
        WRCH(3, acc[4][0].x, acc[4][0].y, acc[4][1].x, 0.f);
      } else {
        WRCH(4, acc[0][1].y, acc[0][2].x, acc[0][2].y, acc[1][1].y);
        WRCH(5, acc[1][2].x, acc[1][2].y, acc[2][1].y, acc[2][2].x);
        WRCH(6, acc[2][2].y, acc[3][1].y, acc[3][2].x, acc[3][2].y);
        WRCH(7, acc[4][1].y, acc[4][2].x, acc[4][2].y, 0.f);
      }
#undef WRCH
    }
    __syncthreads();

    /* gather this pass's bins into persistent packed sums */
    #pragma unroll
    for (int i4 = 0; i4 < 4; ++i4) {
      const int i  = p4*4 + i4;
      const int cp = (i + kf) & 15;
      const int mg = cp - tt + 15;         /* 0..30 */
      const int sg = (mg >> 1) + (mg >> 3);
      const float* Pr = P + (i4*32 + mg)*32;
      #pragma unroll
      for (int ch = 0; ch < 8; ++ch) {
        const int cc = (ch + sg) & 7;
        const float4 x = *(const float4*)(Pr + cc*4);
        s2[ch*2+0] += f32x2{x.x, x.y};
        s2[ch*2+1] += f32x2{x.z, x.w};
      }
    }
    __syncthreads();
  }

  /* ---------- normalize ---------- */
#define SUMF(i) (((i) & 1) ? s2[(i) >> 1].y : s2[(i) >> 1].x)
  float dsc[5][5];
  #pragma unroll
  for (int r = 0; r < 5; ++r) {
    const float inv = 1.0f / (SUMF(16 + r*3 + 2) + EPSF);
    dsc[r][0] = SUMF(r*3+0)    * inv;
    dsc[r][1] = SUMF(r*3+1)    * inv;
    dsc[r][2] = SUMF(r*3+2)    * inv;
    dsc[r][3] = SUMF(16+r*3+0) * inv;
    dsc[r][4] = SUMF(16+r*3+1) * inv;
  }
#undef SUMF

  /* ---------- write A = desc as bf16 (hi only), MFMA A-layout ----------
     Ahi[ic][rot][104]: row = rot, k = r*16+tt (pad 80..95 zero) */
  unsigned short* Ahi = (unsigned short*)smem;          /* [5][16][104] */
  #pragma unroll
  for (int r = 0; r < 5; ++r)
    #pragma unroll
    for (int j = 0; j < 5; ++j) {
      const unsigned hb = bf16_rn_bits(dsc[r][j]);
      const int a = j*1664 + kf*104 + (r*16 + tt);
      Ahi[a] = (unsigned short)hb;
    }
  /* zero-pad k = 80..95 (as u32 pairs) */
  for (int p = tid; p < 640; p += 256) {
    const int ic  = p >> 7;
    const int rem = p & 127;
    const int rot = rem >> 3;
    const int kk  = 80 + ((rem & 7) << 1);
    const int a   = (ic*1664 + rot*104 + kk) >> 1;
    ((unsigned*)Ahi)[a] = 0u;
  }
  __syncthreads();

  /* ---------- conv on MFMA: C[16 rot][80 k'] = A[16x96] @ B[96x80] ----------
     2-term split (A_hi x (W_hi + W_lo)); combo c = (ic, ntile), 25 over 4 waves */
  float* retf = smem + RETF_OFF;
  const int l15 = lane & 15;
  const int kch = lane >> 4;
  #pragma unroll 1
  for (int c = wv; c < 25; c += 4) {
    const int ic = c / 5, nt = c % 5;
    f32x4 accv = {0.f, 0.f, 0.f, 0.f};
    const unsigned short* ah = Ahi + ic*1664 + l15*104 + kch*8;
    const unsigned short* bh = whi + ic*7680 + (nt*16 + l15)*96 + kch*8;
    const unsigned short* bl = wlo + ic*7680 + (nt*16 + l15)*96 + kch*8;
    #pragma unroll
    for (int ks = 0; ks < 3; ++ks) {
      const short8 a_hi = *(const short8*)(ah + ks*32);
      const short8 b_hi = *(const short8*)(bh + ks*32);
      const short8 b_lo = *(const short8*)(bl + ks*32);
      accv = __builtin_amdgcn_mfma_f32_16x16x32_bf16(a_hi, b_hi, accv, 0, 0, 0);
      accv = __builtin_amdgcn_mfma_f32_16x16x32_bf16(a_hi, b_lo, accv, 0, 0, 0);
    }
    /* max over 16 rotations: rows = (lane>>4)*4 + reg */
    float mx = fmaxf(fmaxf(accv[0], accv[1]), fmaxf(accv[2], accv[3]));
    mx = fmaxf(mx, __shfl_xor(mx, 16));
    mx = fmaxf(mx, __shfl_xor(mx, 32));
    if (lane < 16) {
      const int kp = nt*16 + l15;
      retf[kp*5 + ic] = fmaxf(mx + bc[ic*KDIM + kp], 0.0f);
    }
  }
  __syncthreads();

  /* ---------- FC1 (400->80), 3 partials per output ---------- */
  float* ret1p = smem + RET1P_OFF;     /* [3][80] */
  if (tid < 240) {
    const int k    = tid % 80;
    const int part = tid / 80;
    const int o0 = (part == 2) ? 268 : part*132;
    const int o1 = (part == 0) ? 132 : ((part == 1) ? 268 : 400);
    float s1 = 0.0f;
    for (int o = o0; o < o1; o += 4) {
      const float4 r4 = *(const float4*)(retf + o);
      s1 += r4.x * W1[(o+0)*KDIM + k];
      s1 += r4.y * W1[(o+1)*KDIM + k];
      s1 += r4.z * W1[(o+2)*KDIM + k];
      s1 += r4.w * W1[(o+3)*KDIM + k];
    }
    ret1p[part*80 + k] = s1;
  }
  __syncthreads();
  float* ret1 = smem;                  /* reuse dead A region */
  if (tid < KDIM)
    ret1[tid] = fmaxf(ret1p[tid] + ret1p[80+tid] + ret1p[160+tid] + b1[tid], 0.0f);
  __syncthreads();

  /* ---------- FC2 (80->5) ---------- */
  if (tid < NFEAT) {
    float s2f = b2[tid];
    #pragma unroll 8
    for (int k2 = 0; k2 < KDIM; ++k2)
      s2f += ret1[k2] * W2[k2*NFEAT + tid];
    out[(size_t)b*NFEAT + tid] = fmaxf(s2f, 0.0f);
  }
}

extern "C" void kernel_launch(void* const* d_in, const int* in_sizes, int n_in,
                              void* d_out, int out_size, void* d_ws, size_t ws_size,
                              hipStream_t stream) {
  const float* feat    = (const float*)d_in[0];
  const float* rho     = (const float*)d_in[1];
  const float* theta   = (const float*)d_in[2];
  const float* mask    = (const float*)d_in[3];
  const float* mu_rho  = (const float*)d_in[4];
  /* d_in[5] = mu_theta: implied by the separable grid */
  const float* sig_rho = (const float*)d_in[6];
  const float* sig_th  = (const float*)d_in[7];
  const float* Wc      = (const float*)d_in[8];
  const float* bc      = (const float*)d_in[9];
  const float* W1      = (const float*)d_in[10];
  const float* b1      = (const float*)d_in[11];
  const float* W2      = (const float*)d_in[12];
  const float* b2      = (const float*)d_in[13];
  float* outp          = (float*)d_out;

  unsigned short* whi = (unsigned short*)d_ws;
  unsigned short* wlo = whi + WT_ELEMS;

  prep_w<<<dim3((WT_ELEMS + 255) / 256), dim3(256), 0, stream>>>(Wc, whi, wlo);

  const int nB = in_sizes[1] / VCNT;   /* 2048 */
  masif_fused<<<dim3(nB), dim3(256), 0, stream>>>(
      feat, rho, theta, mask, mu_rho, sig_rho, sig_th,
      whi, wlo, bc, W1, b1, W2, b2, outp, nB);
}

// Round 20
// 78.047 us; speedup vs baseline: 1.1838x; 1.1838x over previous
//
#include <hip/hip_runtime.h>

#define NFEAT 5
#define KDIM  80
#define VCNT  200
#define EPSF  1e-5f

#define DTH     0.39269908169872414f   /* 2*pi/16 */
#define INV_DTH 2.5464790894703254f    /* 16/(2*pi) */
#define LOG2E   1.4426950408889634f

/* LDS float offsets (27136 B, __launch_bounds__(256,4) -> 4 blocks/CU):
   phase A: [0..81)     wcnt[4][16] + basep[17] (ints)
            [256..2656)  pv[200][12] : f0..4, gr0..4, fv, pad
            [2656..6752) P[4][32][32] (8-chunk add-swizzle cc=(ch+(m>>1)+(m>>3))&7)
            row: [0..15)=group0 (r,{f0,f1,f2}), [16..31)=group1 (r,{f3,f4,S})
   phase B (P dead): ushort Ahi[5][16][104] = float[0..4160)
            [4160..4560) retf[400]
            [4560..4800) ret1p[3][80]
            ret1[80] reuses smem[0..80) after conv */
#define PV_OFF    256
#define P_OFF     2656
#define RETF_OFF  4160
#define RET1P_OFF 4560
#define LDS_F     6752

#define WT_ELEMS  (5*80*96)            /* 38400 per hi/lo plane */

typedef __attribute__((ext_vector_type(8))) short short8;
typedef __attribute__((ext_vector_type(4))) float f32x4;
typedef __attribute__((ext_vector_type(2))) float f32x2;

__device__ __forceinline__ unsigned bf16_rn_bits(float x) {
  const unsigned u = __float_as_uint(x);
  return (u + 0x7FFFu + ((u >> 16) & 1u)) >> 16;
}

/* ---- prep: W_conv -> transposed bf16 hi/lo [5][80 k'][96 k] in d_ws ---- */
__global__ void prep_w(const float* __restrict__ Wc,
                       unsigned short* __restrict__ whi,
                       unsigned short* __restrict__ wlo) {
  const int idx = blockIdx.x * 256 + threadIdx.x;
  if (idx >= WT_ELEMS) return;
  const int k  = idx % 96;
  const int kp = (idx / 96) % 80;
  const int ic = idx / (96 * 80);
  const float w = (k < 80) ? Wc[ic*6400 + k*80 + kp] : 0.0f;
  const unsigned hb = bf16_rn_bits(w);
  const float    hf = __uint_as_float(hb << 16);
  const unsigned lb = bf16_rn_bits(w - hf);
  whi[idx] = (unsigned short)hb;
  wlo[idx] = (unsigned short)lb;
}

__global__ __launch_bounds__(256, 4)
void masif_fused(const float* __restrict__ feat, const float* __restrict__ rho,
                 const float* __restrict__ theta, const float* __restrict__ mask,
                 const float* __restrict__ mu_rho_p,
                 const float* __restrict__ sigma_rho_p,
                 const float* __restrict__ sigma_theta_p,
                 const unsigned short* __restrict__ whi,
                 const unsigned short* __restrict__ wlo,
                 const float* __restrict__ bc,
                 const float* __restrict__ W1, const float* __restrict__ b1,
                 const float* __restrict__ W2, const float* __restrict__ b2,
                 float* __restrict__ out, int nB)
{
  __shared__ __align__(16) float smem[LDS_F];
  int*   wcnt  = (int*)smem;          /* [4][16] per-wave bin counts */
  int*   basep = (int*)smem + 64;     /* [17] */
  float* pv    = smem + PV_OFF;
  float* P     = smem + P_OFF;

  const int b    = blockIdx.x;
  if (b >= nB) return;
  const int tid  = threadIdx.x;
  const int lane = tid & 63;
  const int wv   = tid >> 6;

  const float stg = sigma_theta_p[0];
  const float nist2 = -(1.0f / (stg*stg + EPSF)) * DTH * DTH * LOG2E;

  /* ---------- prologue: per-vertex quantities in registers ---------- */
  int   my_iv = 999;
  float my_fv = 0.f;
  float myf[5], mygr[5];
  if (tid < VCNT) {
    const size_t gbase = (size_t)b * VCNT + tid;
    const float rh = rho[gbase];
    const float mk = mask[gbase];
    const float th = theta[gbase];
    const float sr = sigma_rho_p[0];
    const float nisr = -(1.0f / (sr*sr + EPSF)) * LOG2E;
    const float u = th * INV_DTH;
    int iv = (int)u; if (iv > 15) iv = 15;
    my_iv = iv;
    my_fv = u - (float)iv;
    #pragma unroll
    for (int j = 0; j < NFEAT; ++j) myf[j] = feat[gbase*NFEAT + j];
    #pragma unroll
    for (int r = 0; r < NFEAT; ++r) {
      const float d = rh - mu_rho_p[r*16];
      mygr[r] = exp2f(d*d*nisr) * mk;   /* rho-gauss * mask */
    }
  }

  /* ---------- ballot-based deterministic binning ---------- */
  unsigned long long mybal = 0ull;
  int mycnt = 0;
  #pragma unroll
  for (int bb = 0; bb < 16; ++bb) {
    const unsigned long long bal = __ballot(my_iv == bb);
    if (my_iv == bb) mybal = bal;
    if (lane == bb)  mycnt = (int)__popcll(bal);
  }
  if (lane < 16) wcnt[wv*16 + lane] = mycnt;
  __syncthreads();
  if (tid == 0) {
    int s0 = 0;
    #pragma unroll
    for (int bb = 0; bb < 16; ++bb) {
      basep[bb] = s0;
      s0 += wcnt[bb] + wcnt[16+bb] + wcnt[32+bb] + wcnt[48+bb];
    }
    basep[16] = s0;
  }
  __syncthreads();
  if (tid < VCNT) {
    int rk = (int)__popcll(mybal & ((1ull << lane) - 1ull));
    if (wv > 0) rk += wcnt[my_iv];
    if (wv > 1) rk += wcnt[16 + my_iv];
    if (wv > 2) rk += wcnt[32 + my_iv];
    const int p = basep[my_iv] + rk;
    float* pvr = pv + p*12;
    pvr[0]=myf[0];  pvr[1]=myf[1];  pvr[2]=myf[2];  pvr[3]=myf[3];  pvr[4]=myf[4];
    pvr[5]=mygr[0]; pvr[6]=mygr[1]; pvr[7]=mygr[2]; pvr[8]=mygr[3]; pvr[9]=mygr[4];
    pvr[10]=my_fv;  pvr[11]=0.f;
  }
  __syncthreads();

  /* ---------- single sweep x 4 passes: accumulate 30 ch -> dump P -> gather */
  const int kf  = tid >> 4;            /* gather role: rotation   */
  const int tt  = tid & 15;            /*              theta bin  */
  const int m   = (tid >> 1) & 31;     /* accum role: m-slice     */
  const int s   = tid & 1;             /*             vertex half */
  const int swz = (m >> 1) + (m >> 3); /* add-swizzle base        */
  const float fm = (float)(m - 15);

  f32x2 s2[16];
  #pragma unroll
  for (int q = 0; q < 16; ++q) s2[q] = f32x2{0.f, 0.f};

  #pragma unroll 1
  for (int p4 = 0; p4 < 4; ++p4) {
    const int bin = p4*4 + wv;         /* wave owns one bin per pass */
    const int p0 = basep[bin], p1 = basep[bin+1];
    f32x2 acc[5][3];
    #pragma unroll
    for (int r = 0; r < 5; ++r)
      #pragma unroll
      for (int q = 0; q < 3; ++q) acc[r][q] = f32x2{0.f, 0.f};

    for (int p = p0 + s; p < p1; p += 2) {
      const float4 x0 = *(const float4*)(pv + p*12);
      const float4 x1 = *(const float4*)(pv + p*12 + 4);
      const float4 x2 = *(const float4*)(pv + p*12 + 8);
      const float d = fm + x2.z;
      const float G = exp2f(d*d*nist2);
      const f32x2 v01 = {x0.x, x0.y};     /* f0, f1 */
      const f32x2 v23 = {x0.z, x0.w};     /* f2, f3 */
      const f32x2 v45 = {x1.x, 1.0f};     /* f4, S  */
      const float pa0 = x1.y*G, pa1 = x1.z*G, pa2 = x1.w*G,
                  pa3 = x2.x*G, pa4 = x2.y*G;
      acc[0][0] += v01*pa0; acc[0][1] += v23*pa0; acc[0][2] += v45*pa0;
      acc[1][0] += v01*pa1; acc[1][1] += v23*pa1; acc[1][2] += v45*pa1;
      acc[2][0] += v01*pa2; acc[2][1] += v23*pa2; acc[2][2] += v45*pa2;
      acc[3][0] += v01*pa3; acc[3][1] += v23*pa3; acc[3][2] += v45*pa3;
      acc[4][0] += v01*pa4; acc[4][1] += v23*pa4; acc[4][2] += v45*pa4;
    }

    /* combine the two vertex-halves (lane xor 1) */
    #pragma unroll
    for (int r = 0; r < 5; ++r)
      #pragma unroll
      for (int q = 0; q < 3; ++q) {
        acc[r][q].x += __shfl_xor(acc[r][q].x, 1);
        acc[r][q].y += __shfl_xor(acc[r][q].y, 1);
      }

    /* dump: logical row of 32 floats
         [r*3+0]=f0, [r*3+1]=f1, [r*3+2]=f2, [15]=0
         [16+r*3+0]=f3, [16+r*3+1]=f4, [16+r*3+2]=S, [31]=0
       lane s=0 writes chunks 0-3, s=1 writes chunks 4-7; contents are
       compile-time register refs (no runtime-indexed local array). */
    {
      float* Pb = P + (wv*32 + m)*32;
#define WRCH(CH, A, B, C, D) \
      *(float4*)(Pb + (((CH) + swz) & 7)*4) = make_float4(A, B, C, D)
      if (s == 0) {
        WRCH(0, acc[0][0].x, acc[0][0].y, acc[0][1].x, acc[1][0].x);
        WRCH(1, acc[1][0].y, acc[1][1].x, acc[2][0].x, acc[2][0].y);
        WRCH(2, acc[2][1].x, acc[3][0].x, acc[3][0].y, acc[3][1].x);
        WRCH(3, acc[4][0].x, acc[4][0].y, acc[4][1].x, 0.f);
      } else {
        WRCH(4, acc[0][1].y, acc[0][2].x, acc[0][2].y, acc[1][1].y);
        WRCH(5, acc[1][2].x, acc[1][2].y, acc[2][1].y, acc[2][2].x);
        WRCH(6, acc[2][2].y, acc[3][1].y, acc[3][2].x, acc[3][2].y);
        WRCH(7, acc[4][1].y, acc[4][2].x, acc[4][2].y, 0.f);
      }
#undef WRCH
    }
    __syncthreads();

    /* gather this pass's bins into persistent packed sums */
    #pragma unroll
    for (int i4 = 0; i4 < 4; ++i4) {
      const int i  = p4*4 + i4;
      const int cp = (i + kf) & 15;
      const int mg = cp - tt + 15;         /* 0..30 */
      const int sg = (mg >> 1) + (mg >> 3);
      const float* Pr = P + (i4*32 + mg)*32;
      #pragma unroll
      for (int ch = 0; ch < 8; ++ch) {
        const int cc = (ch + sg) & 7;
        const float4 x = *(const float4*)(Pr + cc*4);
        s2[ch*2+0] += f32x2{x.x, x.y};
        s2[ch*2+1] += f32x2{x.z, x.w};
      }
    }
    __syncthreads();
  }

  /* ---------- normalize ---------- */
#define SUMF(i) (((i) & 1) ? s2[(i) >> 1].y : s2[(i) >> 1].x)
  float dsc[5][5];
  #pragma unroll
  for (int r = 0; r < 5; ++r) {
    const float inv = 1.0f / (SUMF(16 + r*3 + 2) + EPSF);
    dsc[r][0] = SUMF(r*3+0)    * inv;
    dsc[r][1] = SUMF(r*3+1)    * inv;
    dsc[r][2] = SUMF(r*3+2)    * inv;
    dsc[r][3] = SUMF(16+r*3+0) * inv;
    dsc[r][4] = SUMF(16+r*3+1) * inv;
  }
#undef SUMF

  /* ---------- write A = desc as bf16 (hi only), MFMA A-layout ----------
     Ahi[ic][rot][104]: row = rot, k = r*16+tt (pad 80..95 zero) */
  unsigned short* Ahi = (unsigned short*)smem;          /* [5][16][104] */
  #pragma unroll
  for (int r = 0; r < 5; ++r)
    #pragma unroll
    for (int j = 0; j < 5; ++j) {
      const unsigned hb = bf16_rn_bits(dsc[r][j]);
      const int a = j*1664 + kf*104 + (r*16 + tt);
      Ahi[a] = (unsigned short)hb;
    }
  /* zero-pad k = 80..95 (as u32 pairs) */
  for (int p = tid; p < 640; p += 256) {
    const int ic  = p >> 7;
    const int rem = p & 127;
    const int rot = rem >> 3;
    const int kk  = 80 + ((rem & 7) << 1);
    const int a   = (ic*1664 + rot*104 + kk) >> 1;
    ((unsigned*)Ahi)[a] = 0u;
  }
  __syncthreads();

  /* ---------- conv on MFMA: C[16 rot][80 k'] = A[16x96] @ B[96x80] ----------
     2-term split (A_hi x (W_hi + W_lo)); combo c = (ic, ntile), 25 over 4 waves */
  float* retf = smem + RETF_OFF;
  const int l15 = lane & 15;
  const int kch = lane >> 4;
  #pragma unroll 1
  for (int c = wv; c < 25; c += 4) {
    const int ic = c / 5, nt = c % 5;
    f32x4 accv = {0.f, 0.f, 0.f, 0.f};
    const unsigned short* ah = Ahi + ic*1664 + l15*104 + kch*8;
    const unsigned short* bh = whi + ic*7680 + (nt*16 + l15)*96 + kch*8;
    const unsigned short* bl = wlo + ic*7680 + (nt*16 + l15)*96 + kch*8;
    #pragma unroll
    for (int ks = 0; ks < 3; ++ks) {
      const short8 a_hi = *(const short8*)(ah + ks*32);
      const short8 b_hi = *(const short8*)(bh + ks*32);
      const short8 b_lo = *(const short8*)(bl + ks*32);
      accv = __builtin_amdgcn_mfma_f32_16x16x32_bf16(a_hi, b_hi, accv, 0, 0, 0);
      accv = __builtin_amdgcn_mfma_f32_16x16x32_bf16(a_hi, b_lo, accv, 0, 0, 0);
    }
    /* max over 16 rotations: rows = (lane>>4)*4 + reg */
    float mx = fmaxf(fmaxf(accv[0], accv[1]), fmaxf(accv[2], accv[3]));
    mx = fmaxf(mx, __shfl_xor(mx, 16));
    mx = fmaxf(mx, __shfl_xor(mx, 32));
    if (lane < 16) {
      const int kp = nt*16 + l15;
      retf[kp*5 + ic] = fmaxf(mx + bc[ic*KDIM + kp], 0.0f);
    }
  }
  __syncthreads();

  /* ---------- FC1 (400->80), 3 partials per output ---------- */
  float* ret1p = smem + RET1P_OFF;     /* [3][80] */
  if (tid < 240) {
    const int k    = tid % 80;
    const int part = tid / 80;
    const int o0 = (part == 2) ? 268 : part*132;
    const int o1 = (part == 0) ? 132 : ((part == 1) ? 268 : 400);
    float s1 = 0.0f;
    for (int o = o0; o < o1; o += 4) {
      const float4 r4 = *(const float4*)(retf + o);
      s1 += r4.x * W1[(o+0)*KDIM + k];
      s1 += r4.y * W1[(o+1)*KDIM + k];
      s1 += r4.z * W1[(o+2)*KDIM + k];
      s1 += r4.w * W1[(o+3)*KDIM + k];
    }
    ret1p[part*80 + k] = s1;
  }
  __syncthreads();
  float* ret1 = smem;                  /* reuse dead A region */
  if (tid < KDIM)
    ret1[tid] = fmaxf(ret1p[tid] + ret1p[80+tid] + ret1p[160+tid] + b1[tid], 0.0f);
  __syncthreads();

  /* ---------- FC2 (80->5) ---------- */
  if (tid < NFEAT) {
    float s2f = b2[tid];
    #pragma unroll 8
    for (int k2 = 0; k2 < KDIM; ++k2)
      s2f += ret1[k2] * W2[k2*NFEAT + tid];
    out[(size_t)b*NFEAT + tid] = fmaxf(s2f, 0.0f);
  }
}

extern "C" void kernel_launch(void* const* d_in, const int* in_sizes, int n_in,
                              void* d_out, int out_size, void* d_ws, size_t ws_size,
                              hipStream_t stream) {
  const float* feat    = (const float*)d_in[0];
  const float* rho     = (const float*)d_in[1];
  const float* theta   = (const float*)d_in[2];
  const float* mask    = (const float*)d_in[3];
  const float* mu_rho  = (const float*)d_in[4];
  /* d_in[5] = mu_theta: implied by the separable grid */
  const float* sig_rho = (const float*)d_in[6];
  const float* sig_th  = (const float*)d_in[7];
  const float* Wc      = (const float*)d_in[8];
  const float* bc      = (const float*)d_in[9];
  const float* W1      = (const float*)d_in[10];
  const float* b1      = (const float*)d_in[11];
  const float* W2      = (const float*)d_in[12];
  const float* b2      = (const float*)d_in[13];
  float* outp          = (float*)d_out;

  unsigned short* whi = (unsigned short*)d_ws;
  unsigned short* wlo = whi + WT_ELEMS;

  prep_w<<<dim3((WT_ELEMS + 255) / 256), dim3(256), 0, stream>>>(Wc, whi, wlo);

  const int nB = in_sizes[1] / VCNT;   /* 2048 */
  masif_fused<<<dim3(nB), dim3(256), 0, stream>>>(
      feat, rho, theta, mask, mu_rho, sig_rho, sig_th,
      whi, wlo, bc, W1, b1, W2, b2, outp, nB);
}

// Round 21
// 76.916 us; speedup vs baseline: 1.2012x; 1.0147x over previous
//
#include <hip/hip_runtime.h>

#define NFEAT 5
#define KDIM  80
#define VCNT  200
#define EPSF  1e-5f

#define DTH     0.39269908169872414f   /* 2*pi/16 */
#define INV_DTH 2.5464790894703254f    /* 16/(2*pi) */
#define LOG2E   1.4426950408889634f

/* LDS float offsets (27136 B, __launch_bounds__(256,4) -> 4 blocks/CU):
   phase A: [0..81)     wcnt[4][16] + basep[17] (ints)
            [256..2656)  pv[200][12] : f0..4, gr0..4, fv, pad
            [2656..6752) P[4][32][32] (8-chunk balanced swizzle cc=(ch+m)&7)
            row: [0..15)=group0 (r,{f0,f1,f2}), [16..31)=group1 (r,{f3,f4,S})
   phase B (P dead): ushort Ahi[5][16][104] = float[0..4160)
            [4160..4560) retf[400]
            [4560..4800) ret1p[3][80]
            ret1[80] reuses smem[0..80) after conv */
#define PV_OFF    256
#define P_OFF     2656
#define RETF_OFF  4160
#define RET1P_OFF 4560
#define LDS_F     6752

#define WT_ELEMS  (5*80*96)            /* 38400 per hi/lo plane */

typedef __attribute__((ext_vector_type(8))) short short8;
typedef __attribute__((ext_vector_type(4))) float f32x4;
typedef __attribute__((ext_vector_type(2))) float f32x2;

__device__ __forceinline__ unsigned bf16_rn_bits(float x) {
  const unsigned u = __float_as_uint(x);
  return (u + 0x7FFFu + ((u >> 16) & 1u)) >> 16;
}

/* ---- prep: W_conv -> transposed bf16 hi/lo [5][80 k'][96 k] in d_ws ---- */
__global__ void prep_w(const float* __restrict__ Wc,
                       unsigned short* __restrict__ whi,
                       unsigned short* __restrict__ wlo) {
  const int idx = blockIdx.x * 256 + threadIdx.x;
  if (idx >= WT_ELEMS) return;
  const int k  = idx % 96;
  const int kp = (idx / 96) % 80;
  const int ic = idx / (96 * 80);
  const float w = (k < 80) ? Wc[ic*6400 + k*80 + kp] : 0.0f;
  const unsigned hb = bf16_rn_bits(w);
  const float    hf = __uint_as_float(hb << 16);
  const unsigned lb = bf16_rn_bits(w - hf);
  whi[idx] = (unsigned short)hb;
  wlo[idx] = (unsigned short)lb;
}

__global__ __launch_bounds__(256, 4)
void masif_fused(const float* __restrict__ feat, const float* __restrict__ rho,
                 const float* __restrict__ theta, const float* __restrict__ mask,
                 const float* __restrict__ mu_rho_p,
                 const float* __restrict__ sigma_rho_p,
                 const float* __restrict__ sigma_theta_p,
                 const unsigned short* __restrict__ whi,
                 const unsigned short* __restrict__ wlo,
                 const float* __restrict__ bc,
                 const float* __restrict__ W1, const float* __restrict__ b1,
                 const float* __restrict__ W2, const float* __restrict__ b2,
                 float* __restrict__ out, int nB)
{
  __shared__ __align__(16) float smem[LDS_F];
  int*   wcnt  = (int*)smem;          /* [4][16] per-wave bin counts */
  int*   basep = (int*)smem + 64;     /* [17] */
  float* pv    = smem + PV_OFF;
  float* P     = smem + P_OFF;

  const int b    = blockIdx.x;
  if (b >= nB) return;
  const int tid  = threadIdx.x;
  const int lane = tid & 63;
  const int wv   = tid >> 6;

  const float stg = sigma_theta_p[0];
  const float nist2 = -(1.0f / (stg*stg + EPSF)) * DTH * DTH * LOG2E;

  /* ---------- prologue: per-vertex quantities in registers ---------- */
  int   my_iv = 999;
  float my_fv = 0.f;
  float myf[5], mygr[5];
  if (tid < VCNT) {
    const size_t gbase = (size_t)b * VCNT + tid;
    const float rh = rho[gbase];
    const float mk = mask[gbase];
    const float th = theta[gbase];
    const float sr = sigma_rho_p[0];
    const float nisr = -(1.0f / (sr*sr + EPSF)) * LOG2E;
    const float u = th * INV_DTH;
    int iv = (int)u; if (iv > 15) iv = 15;
    my_iv = iv;
    my_fv = u - (float)iv;
    #pragma unroll
    for (int j = 0; j < NFEAT; ++j) myf[j] = feat[gbase*NFEAT + j];
    #pragma unroll
    for (int r = 0; r < NFEAT; ++r) {
      const float d = rh - mu_rho_p[r*16];
      mygr[r] = exp2f(d*d*nisr) * mk;   /* rho-gauss * mask */
    }
  }

  /* ---------- ballot-based deterministic binning ---------- */
  unsigned long long mybal = 0ull;
  int mycnt = 0;
  #pragma unroll
  for (int bb = 0; bb < 16; ++bb) {
    const unsigned long long bal = __ballot(my_iv == bb);
    if (my_iv == bb) mybal = bal;
    if (lane == bb)  mycnt = (int)__popcll(bal);
  }
  if (lane < 16) wcnt[wv*16 + lane] = mycnt;
  __syncthreads();
  if (tid == 0) {
    int s0 = 0;
    #pragma unroll
    for (int bb = 0; bb < 16; ++bb) {
      basep[bb] = s0;
      s0 += wcnt[bb] + wcnt[16+bb] + wcnt[32+bb] + wcnt[48+bb];
    }
    basep[16] = s0;
  }
  __syncthreads();
  if (tid < VCNT) {
    int rk = (int)__popcll(mybal & ((1ull << lane) - 1ull));
    if (wv > 0) rk += wcnt[my_iv];
    if (wv > 1) rk += wcnt[16 + my_iv];
    if (wv > 2) rk += wcnt[32 + my_iv];
    const int p = basep[my_iv] + rk;
    float* pvr = pv + p*12;
    pvr[0]=myf[0];  pvr[1]=myf[1];  pvr[2]=myf[2];  pvr[3]=myf[3];  pvr[4]=myf[4];
    pvr[5]=mygr[0]; pvr[6]=mygr[1]; pvr[7]=mygr[2]; pvr[8]=mygr[3]; pvr[9]=mygr[4];
    pvr[10]=my_fv;  pvr[11]=0.f;
  }
  __syncthreads();

  /* ---------- single sweep x 4 passes: accumulate 30 ch -> dump P -> gather */
  const int kf  = tid >> 4;            /* gather role: rotation   */
  const int tt  = tid & 15;            /*              theta bin  */
  const int m   = (tid >> 1) & 31;     /* accum role: m-slice     */
  const int s   = tid & 1;             /*             vertex half */
  const int swz = m & 7;               /* balanced swizzle base   */
  const float fm = (float)(m - 15);

  f32x2 s2[16];
  #pragma unroll
  for (int q = 0; q < 16; ++q) s2[q] = f32x2{0.f, 0.f};

  #pragma unroll 1
  for (int p4 = 0; p4 < 4; ++p4) {
    const int bin = p4*4 + wv;         /* wave owns one bin per pass */
    const int p0 = basep[bin], p1 = basep[bin+1];
    f32x2 acc[5][3];
    #pragma unroll
    for (int r = 0; r < 5; ++r)
      #pragma unroll
      for (int q = 0; q < 3; ++q) acc[r][q] = f32x2{0.f, 0.f};

    for (int p = p0 + s; p < p1; p += 2) {
      const float4 x0 = *(const float4*)(pv + p*12);
      const float4 x1 = *(const float4*)(pv + p*12 + 4);
      const float4 x2 = *(const float4*)(pv + p*12 + 8);
      const float d = fm + x2.z;
      const float G = exp2f(d*d*nist2);
      const f32x2 v01 = {x0.x, x0.y};     /* f0, f1 */
      const f32x2 v23 = {x0.z, x0.w};     /* f2, f3 */
      const f32x2 v45 = {x1.x, 1.0f};     /* f4, S  */
      const float pa0 = x1.y*G, pa1 = x1.z*G, pa2 = x1.w*G,
                  pa3 = x2.x*G, pa4 = x2.y*G;
      acc[0][0] += v01*pa0; acc[0][1] += v23*pa0; acc[0][2] += v45*pa0;
      acc[1][0] += v01*pa1; acc[1][1] += v23*pa1; acc[1][2] += v45*pa1;
      acc[2][0] += v01*pa2; acc[2][1] += v23*pa2; acc[2][2] += v45*pa2;
      acc[3][0] += v01*pa3; acc[3][1] += v23*pa3; acc[3][2] += v45*pa3;
      acc[4][0] += v01*pa4; acc[4][1] += v23*pa4; acc[4][2] += v45*pa4;
    }

    /* combine the two vertex-halves (lane xor 1) */
    #pragma unroll
    for (int r = 0; r < 5; ++r)
      #pragma unroll
      for (int q = 0; q < 3; ++q) {
        acc[r][q].x += __shfl_xor(acc[r][q].x, 1);
        acc[r][q].y += __shfl_xor(acc[r][q].y, 1);
      }

    /* dump: logical row of 32 floats
         [r*3+0]=f0, [r*3+1]=f1, [r*3+2]=f2, [15]=0
         [16+r*3+0]=f3, [16+r*3+1]=f4, [16+r*3+2]=S, [31]=0
       lane s=0 writes chunks 0-3, s=1 writes chunks 4-7; contents are
       compile-time register refs (no runtime-indexed local array). */
    {
      float* Pb = P + (wv*32 + m)*32;
#define WRCH(CH, A, B, C, D) \
      *(float4*)(Pb + (((CH) + swz) & 7)*4) = make_float4(A, B, C, D)
      if (s == 0) {
        WRCH(0, acc[0][0].x, acc[0][0].y, acc[0][1].x, acc[1][0].x);
        WRCH(1, acc[1][0].y, acc[1][1].x, acc[2][0].x, acc[2][0].y);
        WRCH(2, acc[2][1].x, acc[3][0].x, acc[3][0].y, acc[3][1].x);
        WRCH(3, acc[4][0].x, acc[4][0].y, acc[4][1].x, 0.f);
      } else {
        WRCH(4, acc[0][1].y, acc[0][2].x, acc[0][2].y, acc[1][1].y);
        WRCH(5, acc[1][2].x, acc[1][2].y, acc[2][1].y, acc[2][2].x);
        WRCH(6, acc[2][2].y, acc[3][1].y, acc[3][2].x, acc[3][2].y);
        WRCH(7, acc[4][1].y, acc[4][2].x, acc[4][2].y, 0.f);
      }
#undef WRCH
    }
    __syncthreads();

    /* gather this pass's bins into persistent packed sums */
    #pragma unroll
    for (int i4 = 0; i4 < 4; ++i4) {
      const int i  = p4*4 + i4;
      const int cp = (i + kf) & 15;
      const int mg = cp - tt + 15;         /* 0..30 */
      const int sg = mg & 7;
      const float* Pr = P + (i4*32 + mg)*32;
      #pragma unroll
      for (int ch = 0; ch < 8; ++ch) {
        const int cc = (ch + sg) & 7;
        const float4 x = *(const float4*)(Pr + cc*4);
        s2[ch*2+0] += f32x2{x.x, x.y};
        s2[ch*2+1] += f32x2{x.z, x.w};
      }
    }
    __syncthreads();
  }

  /* ---------- normalize ---------- */
#define SUMF(i) (((i) & 1) ? s2[(i) >> 1].y : s2[(i) >> 1].x)
  float dsc[5][5];
  #pragma unroll
  for (int r = 0; r < 5; ++r) {
    const float inv = 1.0f / (SUMF(16 + r*3 + 2) + EPSF);
    dsc[r][0] = SUMF(r*3+0)    * inv;
    dsc[r][1] = SUMF(r*3+1)    * inv;
    dsc[r][2] = SUMF(r*3+2)    * inv;
    dsc[r][3] = SUMF(16+r*3+0) * inv;
    dsc[r][4] = SUMF(16+r*3+1) * inv;
  }
#undef SUMF

  /* ---------- write A = desc as bf16 (hi only), MFMA A-layout ----------
     Ahi[ic][rot][104]: row = rot, k = r*16+tt (pad 80..95 zero) */
  unsigned short* Ahi = (unsigned short*)smem;          /* [5][16][104] */
  #pragma unroll
  for (int r = 0; r < 5; ++r)
    #pragma unroll
    for (int j = 0; j < 5; ++j) {
      const unsigned hb = bf16_rn_bits(dsc[r][j]);
      const int a = j*1664 + kf*104 + (r*16 + tt);
      Ahi[a] = (unsigned short)hb;
    }
  /* zero-pad k = 80..95 (as u32 pairs) */
  for (int p = tid; p < 640; p += 256) {
    const int ic  = p >> 7;
    const int rem = p & 127;
    const int rot = rem >> 3;
    const int kk  = 80 + ((rem & 7) << 1);
    const int a   = (ic*1664 + rot*104 + kk) >> 1;
    ((unsigned*)Ahi)[a] = 0u;
  }
  __syncthreads();

  /* ---------- conv on MFMA: C[16 rot][80 k'] = A[16x96] @ B[96x80] ----------
     2-term split (A_hi x (W_hi + W_lo)); combo c = (ic, ntile), 25 over 4 waves */
  float* retf = smem + RETF_OFF;
  const int l15 = lane & 15;
  const int kch = lane >> 4;
  #pragma unroll 1
  for (int c = wv; c < 25; c += 4) {
    const int ic = c / 5, nt = c % 5;
    f32x4 accv = {0.f, 0.f, 0.f, 0.f};
    const unsigned short* ah = Ahi + ic*1664 + l15*104 + kch*8;
    const unsigned short* bh = whi + ic*7680 + (nt*16 + l15)*96 + kch*8;
    const unsigned short* bl = wlo + ic*7680 + (nt*16 + l15)*96 + kch*8;
    #pragma unroll
    for (int ks = 0; ks < 3; ++ks) {
      const short8 a_hi = *(const short8*)(ah + ks*32);
      const short8 b_hi = *(const short8*)(bh + ks*32);
      const short8 b_lo = *(const short8*)(bl + ks*32);
      accv = __builtin_amdgcn_mfma_f32_16x16x32_bf16(a_hi, b_hi, accv, 0, 0, 0);
      accv = __builtin_amdgcn_mfma_f32_16x16x32_bf16(a_hi, b_lo, accv, 0, 0, 0);
    }
    /* max over 16 rotations: rows = (lane>>4)*4 + reg */
    float mx = fmaxf(fmaxf(accv[0], accv[1]), fmaxf(accv[2], accv[3]));
    mx = fmaxf(mx, __shfl_xor(mx, 16));
    mx = fmaxf(mx, __shfl_xor(mx, 32));
    if (lane < 16) {
      const int kp = nt*16 + l15;
      retf[kp*5 + ic] = fmaxf(mx + bc[ic*KDIM + kp], 0.0f);
    }
  }
  __syncthreads();

  /* ---------- FC1 (400->80), 3 partials per output ---------- */
  float* ret1p = smem + RET1P_OFF;     /* [3][80] */
  if (tid < 240) {
    const int k    = tid % 80;
    const int part = tid / 80;
    const int o0 = (part == 2) ? 268 : part*132;
    const int o1 = (part == 0) ? 132 : ((part == 1) ? 268 : 400);
    float s1 = 0.0f;
    for (int o = o0; o < o1; o += 4) {
      const float4 r4 = *(const float4*)(retf + o);
      s1 += r4.x * W1[(o+0)*KDIM + k];
      s1 += r4.y * W1[(o+1)*KDIM + k];
      s1 += r4.z * W1[(o+2)*KDIM + k];
      s1 += r4.w * W1[(o+3)*KDIM + k];
    }
    ret1p[part*80 + k] = s1;
  }
  __syncthreads();
  float* ret1 = smem;                  /* reuse dead A region */
  if (tid < KDIM)
    ret1[tid] = fmaxf(ret1p[tid] + ret1p[80+tid] + ret1p[160+tid] + b1[tid], 0.0f);
  __syncthreads();

  /* ---------- FC2 (80->5) ---------- */
  if (tid < NFEAT) {
    float s2f = b2[tid];
    #pragma unroll 8
    for (int k2 = 0; k2 < KDIM; ++k2)
      s2f += ret1[k2] * W2[k2*NFEAT + tid];
    out[(size_t)b*NFEAT + tid] = fmaxf(s2f, 0.0f);
  }
}

extern "C" void kernel_launch(void* const* d_in, const int* in_sizes, int n_in,
                              void* d_out, int out_size, void* d_ws, size_t ws_size,
                              hipStream_t stream) {
  const float* feat    = (const float*)d_in[0];
  const float* rho     = (const float*)d_in[1];
  const float* theta   = (const float*)d_in[2];
  const float* mask    = (const float*)d_in[3];
  const float* mu_rho  = (const float*)d_in[4];
  /* d_in[5] = mu_theta: implied by the separable grid */
  const float* sig_rho = (const float*)d_in[6];
  const float* sig_th  = (const float*)d_in[7];
  const float* Wc      = (const float*)d_in[8];
  const float* bc      = (const float*)d_in[9];
  const float* W1      = (const float*)d_in[10];
  const float* b1      = (const float*)d_in[11];
  const float* W2      = (const float*)d_in[12];
  const float* b2      = (const float*)d_in[13];
  float* outp          = (float*)d_out;

  unsigned short* whi = (unsigned short*)d_ws;
  unsigned short* wlo = whi + WT_ELEMS;

  prep_w<<<dim3((WT_ELEMS + 255) / 256), dim3(256), 0, stream>>>(Wc, whi, wlo);

  const int nB = in_sizes[1] / VCNT;   /* 2048 */
  masif_fused<<<dim3(nB), dim3(256), 0, stream>>>(
      feat, rho, theta, mask, mu_rho, sig_rho, sig_th,
      whi, wlo, bc, W1, b1, W2, b2, outp, nB);
}